// Round 13
// baseline (135.936 us; speedup 1.0000x reference)
//
#include <hip/hip_runtime.h>
#include <cmath>

#define R_ROWS 1000
#define NCLS   81
#define REGW   (NCLS * 4)
#define SCORE_T 0.05f
#define NMS_T   0.5f
#define NEG_S  -1e9f
#define DETS   100
#define CLIP_V 4.135166556742356f   // log(1000/16)

#define NT     1024                  // threads (16 waves, one CU)
#define CAP_L  3840                  // LDS candidate cap (typ. C_tot ~2500); 30 KiB
#define GCAP   80000                 // global fallback cap (worst case 19000)
#define CHR    64                    // rows per staged chunk (64*81*4 = 20736 B <= U2)
#define NCH    16                    // ceil(1000/64)
#define NBINS  1024
#define SURV_CAP 512

typedef unsigned long long ull;

// ---------- exact-order helpers (no FMA contraction: match numpy/XLA separate rounding) ----------

__device__ __forceinline__ float4 ldp4(const float* __restrict__ prop, int r) {
    return *(const float4*)(prop + r * 4);
}
__device__ __forceinline__ float4 ldr4(const float* __restrict__ reg, int r, int c) {
    return *(const float4*)(reg + r * REGW + 4 * c);
}

__device__ __forceinline__ float4 decode_clip4(float4 p, float4 rr, float wmax, float hmax) {
    float x1 = p.x, y1 = p.y, x2 = p.z, y2 = p.w;
    float w  = __fadd_rn(__fsub_rn(x2, x1), 1.0f);
    float h  = __fadd_rn(__fsub_rn(y2, y1), 1.0f);
    float cx = __fadd_rn(x1, __fmul_rn(0.5f, w));
    float cy = __fadd_rn(y1, __fmul_rn(0.5f, h));
    float dx = rr.x / 10.0f;
    float dy = rr.y / 10.0f;
    float dw = fminf(rr.z / 5.0f, CLIP_V);
    float dh = fminf(rr.w / 5.0f, CLIP_V);
    float pcx = __fadd_rn(__fmul_rn(dx, w), cx);
    float pcy = __fadd_rn(__fmul_rn(dy, h), cy);
    float pw  = __fmul_rn(expf(dw), w);
    float ph  = __fmul_rn(expf(dh), h);
    float ox1 = __fsub_rn(pcx, __fmul_rn(0.5f, pw));
    float oy1 = __fsub_rn(pcy, __fmul_rn(0.5f, ph));
    float ox2 = __fsub_rn(__fadd_rn(pcx, __fmul_rn(0.5f, pw)), 1.0f);
    float oy2 = __fsub_rn(__fadd_rn(pcy, __fmul_rn(0.5f, ph)), 1.0f);
    float4 o;
    o.x = fminf(fmaxf(ox1, 0.0f), wmax);
    o.y = fminf(fmaxf(oy1, 0.0f), hmax);
    o.z = fminf(fmaxf(ox2, 0.0f), wmax);
    o.w = fminf(fmaxf(oy2, 0.0f), hmax);
    return o;
}

__device__ __forceinline__ float iou_legacy(float ax1, float ay1, float ax2, float ay2,
                                            float bx1, float by1, float bx2, float by2) {
    float aw = __fadd_rn(__fsub_rn(ax2, ax1), 1.0f);
    float ah = __fadd_rn(__fsub_rn(ay2, ay1), 1.0f);
    float areaA = __fmul_rn(aw, ah);
    float bw = __fadd_rn(__fsub_rn(bx2, bx1), 1.0f);
    float bh = __fadd_rn(__fsub_rn(by2, by1), 1.0f);
    float areaB = __fmul_rn(bw, bh);
    float ltx = fmaxf(ax1, bx1), lty = fmaxf(ay1, by1);
    float rbx = fminf(ax2, bx2), rby = fminf(ay2, by2);
    float wx = fmaxf(__fadd_rn(__fsub_rn(rbx, ltx), 1.0f), 0.0f);
    float wy = fmaxf(__fadd_rn(__fsub_rn(rby, lty), 1.0f), 0.0f);
    float inter = __fmul_rn(wx, wy);
    float denom = __fsub_rn(__fadd_rn(areaA, areaB), inter);
    return inter / denom;
}

// monotone coarse bin of a positive float score (positive IEEE bits are order-preserving)
__device__ __forceinline__ int bin_of(float s) {
    int idx = (int)(__float_as_uint(s) >> 16) - 0x3D00;   // scores in (0.05,1] -> [76,640]
    return idx < 0 ? 0 : (idx > NBINS - 1 ? NBINS - 1 : idx);
}

__device__ __forceinline__ ull key_of(float s, unsigned f) {
    // (score desc, flat asc) as one monotone u64; valid keys nonzero (score > 0.05)
    return ((ull)__float_as_uint(s) << 32) | (ull)(~f);
}
__device__ __forceinline__ float key_score(ull k) { return __uint_as_float((unsigned)(k >> 32)); }
__device__ __forceinline__ int   key_flat(ull k)  { return (int)(~(unsigned)k); }

// candidate entry: scorebits<<32 | class<<16 | row  (class 1..80, row 0..999; never 0 when valid)
__device__ __forceinline__ ull cand_pack(float sc, int c, int row) {
    return ((ull)__float_as_uint(sc) << 32) | ((ull)c << 16) | (ull)row;
}

// ---------- THE kernel: one block, 1024 threads, everything in order ----------

__global__ __launch_bounds__(NT) void k_mono(const float* __restrict__ logits,
                                             const float* __restrict__ reg,
                                             const float* __restrict__ prop,
                                             const int* __restrict__ piw,
                                             const int* __restrict__ pih,
                                             ull* __restrict__ gA,
                                             ull* __restrict__ gB,
                                             float* __restrict__ out) {
    __shared__ ull A[CAP_L];                         // 30 KiB: candidates -> sorted segments
    __shared__ __align__(16) char U2[CAP_L * 8];     // 30 KiB: chunk f32 / scatter B / select
    __shared__ int clsCnt[NCLS], segOff[NCLS + 1], fillc[NCLS];
    __shared__ int cnt, ovf, sh_cut, sh_mcnt;
    __shared__ float sel_s[DETS]; __shared__ int sel_f[DETS];

    const int t = threadIdx.x, lane = t & 63, wv = t >> 6;
    const float wmax = (float)(*piw - 1), hmax = (float)(*pih - 1);
    float* chunkf = (float*)U2;

    // ===== Phase 1: stream logits once; per-row stats (bit-identical wave reduction);
    //       collect candidates (score > 0.05) into list L =====
    ull* L = A;
    int pass = 0;
    for (;;) {
        if (t == 0) { cnt = 0; ovf = 0; }
        if (t < NCLS) clsCnt[t] = 0;
        __syncthreads();
        const int cap = pass ? GCAP : CAP_L;

        for (int ci = 0; ci < NCH; ++ci) {
            const int rb = ci * CHR;
            int n = R_ROWS - rb; if (n > CHR) n = CHR;
            // coalesced float4 staging
            const float4* src = (const float4*)(logits + rb * NCLS);
            float4* dst = (float4*)chunkf;
            const int nw4 = (n * NCLS) >> 2;
            for (int i = t; i < nw4; i += NT) dst[i] = src[i];
            __syncthreads();
            // wave-per-row stats + candidate emit (reduction identical to proven kernel A)
            for (int r0 = wv; r0 < n; r0 += 16) {
                const int row = rb + r0;
                float v1 = chunkf[r0 * NCLS + lane];
                float v2 = (lane < NCLS - 64) ? chunkf[r0 * NCLS + 64 + lane] : -INFINITY;
                float m = fmaxf(v1, v2);
                #pragma unroll
                for (int off = 32; off; off >>= 1) m = fmaxf(m, __shfl_xor(m, off));
                float s = expf(__fsub_rn(v1, m));
                if (lane < NCLS - 64) s = __fadd_rn(s, expf(__fsub_rn(v2, m)));
                #pragma unroll
                for (int off = 32; off; off >>= 1) s = __fadd_rn(s, __shfl_xor(s, off));
                if (lane >= 1) {                       // classes 1..63
                    float sc = expf(__fsub_rn(v1, m)) / s;
                    if (sc > SCORE_T) {
                        int p = atomicAdd(&cnt, 1);
                        atomicAdd(&clsCnt[lane], 1);
                        if (p < cap) L[p] = cand_pack(sc, lane, row); else ovf = 1;
                    }
                }
                if (lane < NCLS - 64) {                // classes 64..80
                    int c2 = 64 + lane;
                    float sc = expf(__fsub_rn(v2, m)) / s;
                    if (sc > SCORE_T) {
                        int p = atomicAdd(&cnt, 1);
                        atomicAdd(&clsCnt[c2], 1);
                        if (p < cap) L[p] = cand_pack(sc, c2, row); else ovf = 1;
                    }
                }
            }
            __syncthreads();                           // chunkf free for next chunk
        }
        if (!ovf || pass) break;
        L = gA; pass = 1;                              // deterministic slow path (never for this input)
    }
    const int cap_used = pass ? GCAP : CAP_L;
    int C = cnt; if (C > cap_used) C = cap_used;

    // ===== Phase 2: class segments; scatter; exact within-class sort (score desc, row asc) =====
    if (t == 0) {
        int acc = 0;
        for (int c = 1; c <= 80; ++c) { segOff[c] = acc; acc += clsCnt[c]; }
        segOff[81] = acc;
    }
    if (t < NCLS) fillc[t] = 0;
    __syncthreads();

    ull* Bp = pass ? gB : (ull*)U2;                    // chunkf dead; reuse U2
    for (int i = t; i < C; i += NT) {
        ull e = L[i];
        int c = (int)((e >> 16) & 0xFF);
        Bp[segOff[c] + atomicAdd(&fillc[c], 1)] = e;
    }
    __syncthreads();

    for (int i = t; i < C; i += NT) {
        ull e = Bp[i];
        int c = (int)((e >> 16) & 0xFF);
        unsigned si = (unsigned)(e >> 32); int ri = (int)(e & 0xFFFF);
        int o0 = segOff[c], o1 = o0 + clsCnt[c];
        int rank = 0;
        for (int j = o0; j < o1; ++j) {
            ull ej = Bp[j];
            unsigned sj = (unsigned)(ej >> 32); int rj = (int)(ej & 0xFFFF);
            rank += (sj > si) || (sj == si && rj < ri);
        }
        L[o0 + rank] = e;                              // bijective scatter back into A
    }
    __syncthreads();

    // ===== Phase 3: NMS — 16 waves, 5 classes each, fully parallel, zero barriers =====
    for (int c = wv + 1; c <= 80; c += 16) {
        const int off = segOff[c], M = clsCnt[c];
        if (M == 0) continue;
        if (M <= 64) {
            const bool valid = lane < M;
            float b0 = 0, b1 = 0, b2 = 0, b3 = 0;
            if (valid) {
                ull e = L[off + lane];
                int row = (int)(e & 0xFFFF);
                float4 bb = decode_clip4(ldp4(prop, row), ldr4(reg, row, c), wmax, hmax);
                b0 = bb.x; b1 = bb.y; b2 = bb.z; b3 = bb.w;
            }
            ull suppm = 0;
            for (int i = 0; i < M; ++i) {
                if ((suppm >> i) & 1ULL) continue;     // wave-uniform (ballot result)
                float ax1 = __shfl(b0, i), ay1 = __shfl(b1, i);
                float ax2 = __shfl(b2, i), ay2 = __shfl(b3, i);
                bool kill = valid && (lane > i) &&
                            (iou_legacy(ax1, ay1, ax2, ay2, b0, b1, b2, b3) > NMS_T);
                suppm |= __ballot(kill);
            }
            if (valid && ((suppm >> lane) & 1ULL)) L[off + lane] = 0;
        } else {
            // correct-but-slow fallback (recompute boxes; cached loads). Not expected here.
            ull mymask = 0;                            // bit k: suppressed j = lane + 64k
            for (int i = 0; i < M; ++i) {
                ull mo = __shfl(mymask, i & 63);
                if ((mo >> (i >> 6)) & 1ULL) continue; // wave-uniform (shfl-broadcast)
                ull ei = L[off + i];
                int rowi = (int)(ei & 0xFFFF);
                float4 bi = decode_clip4(ldp4(prop, rowi), ldr4(reg, rowi, c), wmax, hmax);
                for (int k = 0;; ++k) {
                    int j = lane + (k << 6);
                    if (j >= M) break;
                    if (j <= i || ((mymask >> k) & 1ULL)) continue;
                    ull ej = L[off + j];
                    int rowj = (int)(ej & 0xFFFF);
                    float4 bj = decode_clip4(ldp4(prop, rowj), ldr4(reg, rowj, c), wmax, hmax);
                    if (iou_legacy(bi.x, bi.y, bi.z, bi.w, bj.x, bj.y, bj.z, bj.w) > NMS_T)
                        mymask |= (1ULL << k);
                }
            }
            for (int k = 0;; ++k) {
                int j = lane + (k << 6);
                if (j >= M) break;
                if ((mymask >> k) & 1ULL) L[off + j] = 0;
            }
        }
    }
    __syncthreads();

    // ===== Phase 4: top-100 selection (histogram cutoff + exact rank), finalize =====
    int* hist = (int*)U2;
    int* cs   = (int*)(U2 + 4096);
    ull* cks  = (ull*)(U2 + 8192);
    for (int b = t; b < NBINS; b += NT) hist[b] = 0;
    if (t == 0) { sh_cut = 0; sh_mcnt = 0; }
    __syncthreads();
    for (int i = t; i < C; i += NT) {
        ull e = L[i];
        if (e) atomicAdd(&hist[bin_of(__uint_as_float((unsigned)(e >> 32)))], 1);
    }
    __syncthreads();
    // suffix scan over 1024 bins with 1024 threads
    cs[t] = hist[t];
    __syncthreads();
    for (int off = 1; off < NBINS; off <<= 1) {
        int x = cs[t] + ((t + off < NBINS) ? cs[t + off] : 0);
        __syncthreads();
        cs[t] = x;
        __syncthreads();
    }
    const int K = cs[0];                               // total kept
    const int target = (K < DETS) ? K : DETS;
    if (target > 0 && cs[t] >= target && (t == NBINS - 1 || cs[t + 1] < target)) sh_cut = t;
    __syncthreads();
    const int cut = sh_cut;                            // survivors (bin >= cut) ⊇ top-target

    for (int i = t; i < C; i += NT) {
        ull e = L[i]; if (!e) continue;
        float sc = __uint_as_float((unsigned)(e >> 32));
        if (bin_of(sc) >= cut) {
            int p = atomicAdd(&sh_mcnt, 1);
            if (p < SURV_CAP) {
                int c = (int)((e >> 16) & 0xFF), row = (int)(e & 0xFFFF);
                cks[p] = key_of(sc, (unsigned)((c - 1) * R_ROWS + row));
            }
        }
    }
    __syncthreads();
    const int Mc = sh_mcnt;

    if (Mc <= SURV_CAP) {
        int Mp = (Mc + 3) & ~3;
        if (t < Mp - Mc) cks[Mc + t] = 0;              // pad: key 0 never outranks a real key
        __syncthreads();
        for (int i = t; i < Mc; i += NT) {
            ull ki = cks[i]; int r = 0;
            for (int j = 0; j < Mp; j += 4)
                r += (int)(cks[j] > ki) + (int)(cks[j + 1] > ki)
                   + (int)(cks[j + 2] > ki) + (int)(cks[j + 3] > ki);
            if (r < DETS) { sel_s[r] = key_score(ki); sel_f[r] = key_flat(ki); }
        }
    } else {
        // degenerate tie flood: exact rank vs all kept (on-the-fly conversion)
        for (int i = t; i < C; i += NT) {
            ull e = L[i]; if (!e) continue;
            float sc = __uint_as_float((unsigned)(e >> 32));
            if (bin_of(sc) < cut) continue;
            int c = (int)((e >> 16) & 0xFF), row = (int)(e & 0xFFFF);
            ull ki = key_of(sc, (unsigned)((c - 1) * R_ROWS + row));
            int r = 0;
            for (int j = 0; j < C; ++j) {
                ull ej = L[j]; if (!ej) continue;
                float sj = __uint_as_float((unsigned)(ej >> 32));
                int cj = (int)((ej >> 16) & 0xFF), rj = (int)(ej & 0xFFFF);
                r += (int)(key_of(sj, (unsigned)((cj - 1) * R_ROWS + rj)) > ki);
            }
            if (r < DETS) { sel_s[r] = key_score(ki); sel_f[r] = key_flat(ki); }
        }
    }
    __syncthreads();

    // tail-fill (only when K < 100: then cut==0, Mc==K, cks holds ALL kept keys)
    if (t == 0 && target < DETS) {
        int n = target, f = 0;
        while (n < DETS) {
            bool used = false;
            for (int q = 0; q < target; ++q) if (key_flat(cks[q]) == f) { used = true; break; }
            if (!used) { sel_s[n] = NEG_S; sel_f[n] = f; n++; }
            f++;
        }
    }
    __syncthreads();

    // decode + write 600 outputs
    if (t < DETS) {
        int f = sel_f[t];
        int c2 = f / R_ROWS;
        int r  = f % R_ROWS;
        float4 b = decode_clip4(ldp4(prop, r), ldr4(reg, r, c2 + 1), wmax, hmax);
        out[t] = sel_s[t];
        out[DETS + 4 * t + 0] = b.x;
        out[DETS + 4 * t + 1] = b.y;
        out[DETS + 4 * t + 2] = b.z;
        out[DETS + 4 * t + 3] = b.w;
        out[DETS * 5 + t] = (float)(c2 + 1);
    }
}

// ---------- host launcher ----------

extern "C" void kernel_launch(void* const* d_in, const int* in_sizes, int n_in,
                              void* d_out, int out_size, void* d_ws, size_t ws_size,
                              hipStream_t stream) {
    (void)in_sizes; (void)n_in; (void)out_size; (void)ws_size;
    const float* logits = (const float*)d_in[0];
    const float* reg    = (const float*)d_in[1];
    const float* prop   = (const float*)d_in[2];
    const int*   piw    = (const int*)d_in[3];
    const int*   pih    = (const int*)d_in[4];
    float* out = (float*)d_out;

    // ws used ONLY by the (practically unreachable) overflow fallback; overwritten
    // before read there, single-block => no coherence concerns, no init needed.
    ull* gA = (ull*)d_ws;
    ull* gB = (ull*)((char*)d_ws + (size_t)GCAP * 8);

    k_mono<<<dim3(1), dim3(NT), 0, stream>>>(logits, reg, prop, piw, pih, gA, gB, out);
}

// Round 14
// 42.993 us; speedup vs baseline: 3.1618x; 3.1618x over previous
//
#include <hip/hip_runtime.h>
#include <cmath>

#define R_ROWS 1000
#define NCLS   81
#define REGW   (NCLS * 4)
#define SCORE_T 0.05f
#define NMS_T   0.5f
#define NEG_S  -1e9f
#define DETS   100
#define CLIP_V 4.135166556742356f   // log(1000/16)
#define SLOTS  1000                  // per-class list region (max possible = R_ROWS)
#define NBLK_CLS 80                  // classes 1..80 -> blocks 0..79

#define NBINS    1024
#define CK_CAP   2560                // LDS key buffer in selector (typ. K ~ 2000)
#define SURV_CAP 512                 // LDS survivor buffer (typ. Mc ~ 150)

typedef unsigned long long ull;

// ---------- exact-order helpers (no FMA contraction: match numpy/XLA separate rounding) ----------

__device__ __forceinline__ float4 decode_clip(const float* __restrict__ prop,
                                              const float* __restrict__ reg,
                                              int r, int ccol, float wmax, float hmax) {
    float x1 = prop[r * 4 + 0], y1 = prop[r * 4 + 1];
    float x2 = prop[r * 4 + 2], y2 = prop[r * 4 + 3];
    float w  = __fadd_rn(__fsub_rn(x2, x1), 1.0f);
    float h  = __fadd_rn(__fsub_rn(y2, y1), 1.0f);
    float cx = __fadd_rn(x1, __fmul_rn(0.5f, w));
    float cy = __fadd_rn(y1, __fmul_rn(0.5f, h));
    const float* rr = reg + r * REGW + 4 * ccol;
    float dx = rr[0] / 10.0f;
    float dy = rr[1] / 10.0f;
    float dw = fminf(rr[2] / 5.0f, CLIP_V);
    float dh = fminf(rr[3] / 5.0f, CLIP_V);
    float pcx = __fadd_rn(__fmul_rn(dx, w), cx);
    float pcy = __fadd_rn(__fmul_rn(dy, h), cy);
    float pw  = __fmul_rn(expf(dw), w);
    float ph  = __fmul_rn(expf(dh), h);
    float ox1 = __fsub_rn(pcx, __fmul_rn(0.5f, pw));
    float oy1 = __fsub_rn(pcy, __fmul_rn(0.5f, ph));
    float ox2 = __fsub_rn(__fadd_rn(pcx, __fmul_rn(0.5f, pw)), 1.0f);
    float oy2 = __fsub_rn(__fadd_rn(pcy, __fmul_rn(0.5f, ph)), 1.0f);
    float4 o;
    o.x = fminf(fmaxf(ox1, 0.0f), wmax);
    o.y = fminf(fmaxf(oy1, 0.0f), hmax);
    o.z = fminf(fmaxf(ox2, 0.0f), wmax);
    o.w = fminf(fmaxf(oy2, 0.0f), hmax);
    return o;
}

__device__ __forceinline__ float iou_legacy(float ax1, float ay1, float ax2, float ay2,
                                            float bx1, float by1, float bx2, float by2) {
    float aw = __fadd_rn(__fsub_rn(ax2, ax1), 1.0f);
    float ah = __fadd_rn(__fsub_rn(ay2, ay1), 1.0f);
    float areaA = __fmul_rn(aw, ah);
    float bw = __fadd_rn(__fsub_rn(bx2, bx1), 1.0f);
    float bh = __fadd_rn(__fsub_rn(by2, by1), 1.0f);
    float areaB = __fmul_rn(bw, bh);
    float ltx = fmaxf(ax1, bx1), lty = fmaxf(ay1, by1);
    float rbx = fminf(ax2, bx2), rby = fminf(ay2, by2);
    float wx = fmaxf(__fadd_rn(__fsub_rn(rbx, ltx), 1.0f), 0.0f);
    float wy = fmaxf(__fadd_rn(__fsub_rn(rby, lty), 1.0f), 0.0f);
    float inter = __fmul_rn(wx, wy);
    float denom = __fsub_rn(__fadd_rn(areaA, areaB), inter);
    return inter / denom;
}

// monotone coarse bin of a positive float score (positive IEEE bits are order-preserving)
__device__ __forceinline__ int bin_of(float s) {
    int idx = (int)(__float_as_uint(s) >> 16) - 0x3D00;   // scores in (0.05,1] -> [76,640]
    return idx < 0 ? 0 : (idx > NBINS - 1 ? NBINS - 1 : idx);
}

// key = (score desc, flat asc) as one monotone u64; also == (score desc, row asc)
// within one class, so it is BOTH the NMS sort comparator and the top-k comparator.
__device__ __forceinline__ ull key_of(float s, unsigned f) {
    return ((ull)__float_as_uint(s) << 32) | (ull)(~f);
}
__device__ __forceinline__ float key_score(ull k) { return __uint_as_float((unsigned)(k >> 32)); }
__device__ __forceinline__ int   key_flat(ull k)  { return (int)(~(unsigned)k); }

// device-scope (sc1) coherent accesses. R7 lesson: NEVER spin-poll these. Used only for
// one-shot post-RMW-handoff reads of deterministic data (R9-proven pattern).
__device__ __forceinline__ void dev_store_u64(ull* p, ull v) {
    __hip_atomic_store(p, v, __ATOMIC_RELAXED, __HIP_MEMORY_SCOPE_AGENT);
}
__device__ __forceinline__ ull dev_load_u64(const ull* p) {
    return __hip_atomic_load(p, __ATOMIC_RELAXED, __HIP_MEMORY_SCOPE_AGENT);
}
__device__ __forceinline__ void dev_store_i32(int* p, int v) {
    __hip_atomic_store(p, v, __ATOMIC_RELAXED, __HIP_MEMORY_SCOPE_AGENT);
}

// upper-bound search: returns c with koff[c] <= g < koff[c+1]
__device__ __forceinline__ int find_class(const int* koff, int g) {
    int lo = 0, hi = NBLK_CLS;
    while (hi - lo > 1) { int mid = (lo + hi) >> 1; if (g >= koff[mid]) lo = mid; else hi = mid; }
    return lo;
}

// ---------- Kernel A: per-row stats + DIRECT candidate emission (scores in-register) ----------
// 1000 blocks x 64. Appends key(score,flat) to per-class lists via global atomicAdd.
// Append order is nondeterministic but kernel B's exact rank-sort restores a unique
// total order (strict comparator, one entry per (row,class)) -> deterministic output.

__global__ __launch_bounds__(64) void k_stats_emit(const float* __restrict__ logits,
                                                   int* __restrict__ cnt,      // [81]
                                                   ull* __restrict__ klistA) {
    int r = blockIdx.x;
    int l = threadIdx.x;
    float v1 = logits[r * NCLS + l];
    float v2 = (l < NCLS - 64) ? logits[r * NCLS + 64 + l] : -INFINITY;
    float m = fmaxf(v1, v2);
    #pragma unroll
    for (int off = 32; off; off >>= 1) m = fmaxf(m, __shfl_xor(m, off));
    float s = expf(__fsub_rn(v1, m));
    if (l < NCLS - 64) s = __fadd_rn(s, expf(__fsub_rn(v2, m)));
    #pragma unroll
    for (int off = 32; off; off >>= 1) s = __fadd_rn(s, __shfl_xor(s, off));

    if (l >= 1) {                                    // classes 1..63
        float sc = expf(__fsub_rn(v1, m)) / s;
        if (sc > SCORE_T) {
            int p = atomicAdd(&cnt[l], 1);           // p < 1000 structurally
            klistA[(size_t)(l - 1) * SLOTS + p] = key_of(sc, (unsigned)((l - 1) * R_ROWS + r));
        }
    }
    if (l < NCLS - 64) {                             // classes 64..80
        int c = 64 + l;
        float sc = expf(__fsub_rn(v2, m)) / s;
        if (sc > SCORE_T) {
            int p = atomicAdd(&cnt[c], 1);
            klistA[(size_t)(c - 1) * SLOTS + p] = key_of(sc, (unsigned)((c - 1) * R_ROWS + r));
        }
    }
}

// ---------- Kernel B: 80 class blocks — sort, decode, NMS; last block selects ----------

__global__ __launch_bounds__(256) void k_nms_select(const float* __restrict__ reg,
                                                    const float* __restrict__ prop,
                                                    const int* __restrict__ piw,
                                                    const int* __restrict__ pih,
                                                    const int* __restrict__ cnt,
                                                    const ull* __restrict__ klistA,
                                                    ull* __restrict__ klistB,
                                                    int* __restrict__ kcount,
                                                    int* __restrict__ done,
                                                    float* __restrict__ out) {
    __shared__ ull ku[SLOTS];      // unsorted keys
    __shared__ ull ks[SLOTS];      // sorted keys (desc)
    __shared__ float bx4[SLOTS][4];
    __shared__ int   supp[SLOTS];
    __shared__ int   sh_last;
    // selector-phase LDS
    __shared__ int   koff[NBLK_CLS + 1];
    __shared__ int   cs[256];
    __shared__ int   hist_s[NBINS];
    __shared__ ull   ck[CK_CAP + 4];
    __shared__ ull   cks[SURV_CAP + 4];
    __shared__ float sel_s[DETS]; __shared__ int sel_f[DETS];
    __shared__ int   sh_cut, sh_mcnt;

    const int cidx = blockIdx.x;       // 0..79
    const int ccol = cidx + 1;
    const int t    = threadIdx.x;
    const int lane = t & 63;
    const int wv   = t >> 6;
    const float wmax = (float)(*piw - 1);
    const float hmax = (float)(*pih - 1);

    int M = cnt[ccol]; if (M > SLOTS) M = SLOTS;     // plain load across dispatch boundary

    // load keys (coalesced, typ. M ~ 31)
    for (int i = t; i < M; i += 256) ku[i] = klistA[(size_t)cidx * SLOTS + i];
    __syncthreads();

    // exact rank sort: u64 desc == (score desc, row asc)
    for (int i = t; i < M; i += 256) {
        ull ki = ku[i];
        int rank = 0;
        for (int j = 0; j < M; j++) rank += (int)(ku[j] > ki);
        ks[rank] = ki;
    }
    __syncthreads();

    // decode + clip
    for (int i = t; i < M; i += 256) {
        int row = key_flat(ks[i]) - cidx * R_ROWS;
        float4 b = decode_clip(prop, reg, row, ccol, wmax, hmax);
        bx4[i][0] = b.x; bx4[i][1] = b.y; bx4[i][2] = b.z; bx4[i][3] = b.w;
        supp[i] = 0;
    }
    __syncthreads();

    // NMS + write kept keys to fixed per-class slots
    if (M <= 64) {
        if (wv == 0) {                               // wave-ballot NMS (validated R7-R13)
            const bool valid = lane < M;
            float b0 = 0, b1 = 0, b2 = 0, b3 = 0; ull ke = 0;
            if (valid) { b0 = bx4[lane][0]; b1 = bx4[lane][1]; b2 = bx4[lane][2]; b3 = bx4[lane][3];
                         ke = ks[lane]; }
            ull suppm = 0;
            for (int i = 0; i < M; ++i) {
                if ((suppm >> i) & 1ULL) continue;   // wave-uniform (ballot result)
                float ax1 = __shfl(b0, i), ay1 = __shfl(b1, i);
                float ax2 = __shfl(b2, i), ay2 = __shfl(b3, i);
                bool kill = valid && (lane > i) &&
                            (iou_legacy(ax1, ay1, ax2, ay2, b0, b1, b2, b3) > NMS_T);
                suppm |= __ballot(kill);
            }
            ull keepm = ~suppm;
            if (M < 64) keepm &= (1ULL << M) - 1ULL;
            if (valid && ((keepm >> lane) & 1ULL)) {
                int pos = __popcll(keepm & ((1ULL << lane) - 1ULL));
                dev_store_u64(&klistB[(size_t)cidx * SLOTS + pos], ke);
            }
            if (lane == 0) dev_store_i32(&kcount[cidx], __popcll(keepm));
        }
    } else {
        for (int i = 0; i < M; i++) {
            if (!supp[i]) {
                float ax1 = bx4[i][0], ay1 = bx4[i][1], ax2 = bx4[i][2], ay2 = bx4[i][3];
                for (int j = i + 1 + t; j < M; j += 256) {
                    if (!supp[j]) {
                        float v = iou_legacy(ax1, ay1, ax2, ay2,
                                             bx4[j][0], bx4[j][1], bx4[j][2], bx4[j][3]);
                        if (v > NMS_T) supp[j] = 1;
                    }
                }
            }
            __syncthreads();
        }
        for (int i = t; i < M; i += 256) {
            if (!supp[i]) {
                int pos = 0;
                for (int j = 0; j < i; ++j) pos += !supp[j];
                dev_store_u64(&klistB[(size_t)cidx * SLOTS + pos], ks[i]);
            }
        }
        if (t == 0) {
            int kc = 0;
            for (int i = 0; i < M; ++i) kc += !supp[i];
            dev_store_i32(&kcount[cidx], kc);
        }
    }

    // ---- last-block handoff: RMW only (R7 lesson) ----
    __syncthreads();   // drains vmcnt(0): all sc1 stores at coherence point
    if (t == 0) sh_last = (atomicAdd(done, 1) == NBLK_CLS - 1) ? 1 : 0;
    __syncthreads();
    if (!sh_last) return;

    // ================= selector (exactly one block: the last to finish) =================
    if (t < NBLK_CLS) cs[t] = atomicAdd(&kcount[t], 0);   // RMW read: always fresh
    for (int b = t; b < NBINS; b += 256) hist_s[b] = 0;
    __syncthreads();
    if (t == 0) {
        int acc = 0;
        for (int c = 0; c < NBLK_CLS; ++c) { koff[c] = acc; acc += cs[c]; }
        koff[NBLK_CLS] = acc;
        sh_cut = 0; sh_mcnt = 0;
    }
    __syncthreads();
    const int K = koff[NBLK_CLS];
    const int target = (K < DETS) ? K : DETS;

    if (K <= CK_CAP) {
        // single sc1 sweep: keys -> LDS + LDS histogram
        for (int g = t; g < K; g += 256) {
            int c = find_class(koff, g);
            ull k = dev_load_u64(&klistB[(size_t)c * SLOTS + (g - koff[c])]);
            ck[g] = k;
            atomicAdd(&hist_s[bin_of(key_score(k))], 1);
        }
        __syncthreads();

        // suffix scan of 1024 bins: S[b] = #keys with bin >= b
        int v0 = hist_s[4 * t], v1 = hist_s[4 * t + 1], v2 = hist_s[4 * t + 2], v3 = hist_s[4 * t + 3];
        int s3 = v3, s2 = v2 + s3, s1 = v1 + s2, s0 = v0 + s1;
        cs[t] = s0;
        __syncthreads();
        for (int off = 1; off < 256; off <<= 1) {
            int x = cs[t] + ((t + off < 256) ? cs[t + off] : 0);
            __syncthreads();
            cs[t] = x;
            __syncthreads();
        }
        int tail = (t < 255) ? cs[t + 1] : 0;
        int S0 = s0 + tail, S1 = s1 + tail, S2 = s2 + tail, S3 = s3 + tail;
        if (target > 0) {
            int best = -1;
            if      (S3 >= target) best = 4 * t + 3;
            else if (S2 >= target) best = 4 * t + 2;
            else if (S1 >= target) best = 4 * t + 1;
            else if (S0 >= target) best = 4 * t;
            if (best >= 0) atomicMax(&sh_cut, best);
        }
        __syncthreads();
        const int cut = sh_cut;   // survivors (bin >= cut) ⊇ top-target

        // compact survivors in-LDS
        for (int g = t; g < K; g += 256) {
            ull k = ck[g];
            if (bin_of(key_score(k)) >= cut) {
                int p = atomicAdd(&sh_mcnt, 1);
                if (p < SURV_CAP) cks[p] = k;
            }
        }
        __syncthreads();
        const int Mc = sh_mcnt;

        if (Mc <= SURV_CAP) {
            int Mp = (Mc + 3) & ~3;
            if (t < Mp - Mc) cks[Mc + t] = 0;   // pad: key 0 never outranks a real key
            __syncthreads();
            for (int i = t; i < Mc; i += 256) {
                ull ki = cks[i];
                int r = 0;
                for (int j = 0; j < Mp; j += 4)
                    r += (int)(cks[j] > ki) + (int)(cks[j + 1] > ki)
                       + (int)(cks[j + 2] > ki) + (int)(cks[j + 3] > ki);
                if (r < DETS) { sel_s[r] = key_score(ki); sel_f[r] = key_flat(ki); }
            }
        } else {
            // degenerate tie flood: rank survivors against full ck (LDS, slower, correct)
            int Kp = (K + 3) & ~3;
            if (t < Kp - K) ck[K + t] = 0;
            __syncthreads();
            for (int g = t; g < K; g += 256) {
                ull ki = ck[g];
                if (bin_of(key_score(ki)) < cut) continue;
                int r = 0;
                for (int j = 0; j < Kp; j += 4)
                    r += (int)(ck[j] > ki) + (int)(ck[j + 1] > ki)
                       + (int)(ck[j + 2] > ki) + (int)(ck[j + 3] > ki);
                if (r < DETS) { sel_s[r] = key_score(ki); sel_f[r] = key_flat(ki); }
            }
        }
    } else {
        // K > CK_CAP (not reachable in practice): exact rank via global sc1 sweeps
        for (int g = t; g < K; g += 256) {
            int c = find_class(koff, g);
            ull ki = dev_load_u64(&klistB[(size_t)c * SLOTS + (g - koff[c])]);
            int r = 0;
            for (int g2 = 0; g2 < K; ++g2) {
                int c2 = find_class(koff, g2);
                r += (int)(dev_load_u64(&klistB[(size_t)c2 * SLOTS + (g2 - koff[c2])]) > ki);
            }
            if (r < DETS) { sel_s[r] = key_score(ki); sel_f[r] = key_flat(ki); }
        }
    }
    __syncthreads();

    // tail-fill (only when K < 100: all K keys survive the cut, so cks holds them all)
    if (t == 0 && target < DETS) {
        int n = target, f = 0;
        while (n < DETS) {
            bool used = false;
            for (int q = 0; q < target; q++) if (key_flat(cks[q]) == f) { used = true; break; }
            if (!used) { sel_s[n] = NEG_S; sel_f[n] = f; n++; }
            f++;
        }
    }
    __syncthreads();

    // decode + write 600 outputs
    if (t < DETS) {
        int f = sel_f[t];
        int c2 = f / R_ROWS;
        int r  = f % R_ROWS;
        float4 b = decode_clip(prop, reg, r, c2 + 1, wmax, hmax);
        out[t] = sel_s[t];
        out[DETS + 4 * t + 0] = b.x;
        out[DETS + 4 * t + 1] = b.y;
        out[DETS + 4 * t + 2] = b.z;
        out[DETS + 4 * t + 3] = b.w;
        out[DETS * 5 + t] = (float)(c2 + 1);
    }
}

// ---------- host launcher ----------

extern "C" void kernel_launch(void* const* d_in, const int* in_sizes, int n_in,
                              void* d_out, int out_size, void* d_ws, size_t ws_size,
                              hipStream_t stream) {
    (void)in_sizes; (void)n_in; (void)out_size; (void)ws_size;
    const float* logits = (const float*)d_in[0];
    const float* reg    = (const float*)d_in[1];
    const float* prop   = (const float*)d_in[2];
    const int*   piw    = (const int*)d_in[3];
    const int*   pih    = (const int*)d_in[4];
    float* out = (float*)d_out;

    // workspace (bytes):
    //   0      done (4) + cnt[81] (324)            <- zeroed by 512B memset node
    //   1024   kcount[80]                          <- overwritten before read (sc1/RMW)
    //   4096   klistA[80*1000] u64 (640 KB)        <- slots written before read
    //   660480 klistB[80*1000] u64 (640 KB)
    char* ws = (char*)d_ws;
    int* done   = (int*)(ws);
    int* cnt    = (int*)(ws + 64);
    int* kcount = (int*)(ws + 1024);
    ull* klistA = (ull*)(ws + 4096);
    ull* klistB = (ull*)(ws + 4096 + (size_t)NBLK_CLS * SLOTS * 8);

    hipMemsetAsync(ws, 0, 512, stream);
    k_stats_emit<<<dim3(R_ROWS), dim3(64), 0, stream>>>(logits, cnt, klistA);
    k_nms_select<<<dim3(NBLK_CLS), dim3(256), 0, stream>>>(reg, prop, piw, pih,
                                                           cnt, klistA, klistB,
                                                           kcount, done, out);
}